// Round 4
// baseline (86.829 us; speedup 1.0000x reference)
//
#include <hip/hip_runtime.h>

typedef __bf16 bf16x8 __attribute__((ext_vector_type(8)));
typedef float f32x4 __attribute__((ext_vector_type(4)));
typedef unsigned short u16x8 __attribute__((ext_vector_type(8)));

#define B_ 32
#define CC 512
#define HW 192
#define C8_ 64
#define NTRI 528
#define NBLK 560
#define TB2 12288   // one 192x32 bf16 tile (64B rows)

__device__ inline unsigned short f2bf(float f) {
    unsigned u = __float_as_uint(f);
    unsigned r = (u + 0x7FFFu + ((u >> 16) & 1u)) >> 16;
    return (unsigned short)r;
}

__device__ inline void gload16(const void* g, void* l) {
    __builtin_amdgcn_global_load_lds(
        (const __attribute__((address_space(1))) unsigned*)g,
        (__attribute__((address_space(3))) unsigned*)l,
        16, 0, 0);
}

// ---------------- Kernel 1: x [B][C][HW] f32 -> xt [B][HW][C] bf16 ----------
// 64m x 64c tiles through LDS: coalesced reads AND 128B-granule writes.
__global__ void k_transpose(const float* __restrict__ x,
                            unsigned short* __restrict__ xt) {
    __shared__ unsigned short tile[64 * 64];
    int b = blockIdx.x / 3, mt = blockIdx.x % 3;
    int m0 = mt * 64, c0 = blockIdx.y * 64;
    int t = threadIdx.x;
    const float* xb = x + (size_t)b * CC * HW + (size_t)c0 * HW + m0;

    int mq = t & 15, cl0 = t >> 4;          // mq: 4-m group, cl0: c within round
    int sw = (mq & 7) << 3;                 // XOR swizzle on c bits 3..5
    #pragma unroll
    for (int rd = 0; rd < 4; ++rd) {
        int cl = rd * 16 + cl0;
        f32x4 v = *(const f32x4*)(xb + cl * HW + mq * 4);   // coalesced over m
        #pragma unroll
        for (int e = 0; e < 4; ++e)
            tile[(mq * 4 + e) * 64 + (cl ^ sw)] = f2bf(v[e]);
    }
    __syncthreads();
    unsigned short* xo = xt + ((size_t)b * HW + m0) * CC + c0;
    int kc = t & 7, mr0 = t >> 3;
    #pragma unroll
    for (int rd = 0; rd < 2; ++rd) {
        int mr = rd * 32 + mr0;
        u16x8 v = *(const u16x8*)&tile[mr * 64 + ((kc << 3) ^ (((mr >> 2) & 7) << 3))];
        *(u16x8*)(xo + (size_t)mr * CC + kc * 8) = v;       // 128B/row coalesced
    }
}

// ---------------- Kernel 2 (fused): gram tiles + PAM ------------------------
// blocks 0..527: triangular (g<=p) 192x192 Gram tile, 4 waves (2x2), 96x96
//   per wave, BK=32 double-buffered via global_load_lds, both-sides XOR swz.
// blocks 528..559: PAM for batch b: q/k proj (MFMA) -> LDS, energy + rowmax.
__global__ __launch_bounds__(256, 2) void gram_pam(
        const unsigned short* __restrict__ xt,
        const float* __restrict__ Wq, const float* __restrict__ bq,
        const float* __restrict__ Wk, const float* __restrict__ bk,
        float* __restrict__ out) {
    __shared__ __attribute__((aligned(16))) char smem[52224];
    int tid = threadIdx.x;
    int w = tid >> 6, lane = tid & 63;
    int l15 = lane & 15, lq = lane >> 4;
    // XCD-aware bijective swizzle (560 = 8 * 70)
    int bid = (blockIdx.x & 7) * 70 + (blockIdx.x >> 3);

    if (bid < NTRI) {
        // ================= GRAM =================
        int idx = bid, g = 0;
        while (idx >= B_ - g) { idx -= B_ - g; ++g; }
        int p = g + idx;
        const unsigned short* xg = xt + (size_t)g * HW * CC;
        const unsigned short* xp = xt + (size_t)p * HW * CC;
        int wr = w >> 1, wc = w & 1;

        // staging: round ci covers rows ci*64 + w*16 + (lane>>2); slot lane&3.
        // logical k-chunk at phys slot s is s ^ ((row>>1)&3); (row>>1)&3 == (lane>>3)&3.
        int chunk = (((lane & 3) ^ ((lane >> 3) & 3)) << 3);
        const unsigned short* agp = xg + ((w << 4) + (lane >> 2)) * CC + chunk;
        const unsigned short* bgp = xp + ((w << 4) + (lane >> 2)) * CC + chunk;

        // fragment read offsets: byte = row*64 + ((lq ^ ((row>>1)&3))<<4); swz term
        // reduces to (lq ^ ((l15>>1)&3)) since row bases are multiples of 16.
        unsigned ssw = (unsigned)((lq ^ ((l15 >> 1) & 3)) << 4);
        unsigned aoff[6], boff[6];
        #pragma unroll
        for (int i = 0; i < 6; ++i)
            aoff[i] = (unsigned)(wr * 96 + i * 16 + l15) * 64 + ssw;
        #pragma unroll
        for (int j = 0; j < 6; ++j)
            boff[j] = (unsigned)(wc * 96 + j * 16 + l15) * 64 + ssw;

        f32x4 acc[6][6];
        #pragma unroll
        for (int i = 0; i < 6; ++i)
            #pragma unroll
            for (int j = 0; j < 6; ++j)
                acc[i][j] = (f32x4){0.f, 0.f, 0.f, 0.f};

        #define STG(buf, k0)                                                   \
            {                                                                  \
                char* ab = smem + (buf) * TB2 + (w << 10);                     \
                char* bb = smem + 2 * TB2 + (buf) * TB2 + (w << 10);           \
                _Pragma("unroll")                                              \
                for (int ci = 0; ci < 3; ++ci) {                               \
                    gload16(agp + (k0) + ci * 64 * CC, ab + ci * 4096);        \
                    gload16(bgp + (k0) + ci * 64 * CC, bb + ci * 4096);        \
                }                                                              \
            }

        STG(0, 0);
        __syncthreads();
        for (int kt = 0; kt < 16; ++kt) {
            int cur = kt & 1;
            if (kt < 15) STG(cur ^ 1, (kt + 1) * 32);
            const char* Ab = smem + cur * TB2;
            const char* Bb = smem + 2 * TB2 + cur * TB2;
            bf16x8 bfr[6];
            #pragma unroll
            for (int j = 0; j < 6; ++j)
                bfr[j] = *(const bf16x8*)(Bb + boff[j]);
            #pragma unroll
            for (int i = 0; i < 6; ++i) {
                bf16x8 a = *(const bf16x8*)(Ab + aoff[i]);
                #pragma unroll
                for (int j = 0; j < 6; ++j)
                    acc[i][j] = __builtin_amdgcn_mfma_f32_16x16x32_bf16(
                        a, bfr[j], acc[i][j], 0, 0, 0);
            }
            __syncthreads();
        }

        // epilogue: col-max over m -> out[g][p][n]; row-max over n -> out[p][g][m]
        float* colbuf = (float*)(smem + 4 * TB2);     // [2][192]
        float* rowbuf = colbuf + 2 * HW;              // [2][192]
        #pragma unroll
        for (int j = 0; j < 6; ++j) {
            float cm = -1e30f;
            #pragma unroll
            for (int i = 0; i < 6; ++i)
                #pragma unroll
                for (int r = 0; r < 4; ++r)
                    cm = fmaxf(cm, acc[i][j][r]);
            cm = fmaxf(cm, __shfl_xor(cm, 16));
            cm = fmaxf(cm, __shfl_xor(cm, 32));
            if (lane < 16) colbuf[wr * HW + wc * 96 + j * 16 + l15] = cm;
        }
        #pragma unroll
        for (int i = 0; i < 6; ++i) {
            float rm[4];
            #pragma unroll
            for (int r = 0; r < 4; ++r) rm[r] = -1e30f;
            #pragma unroll
            for (int j = 0; j < 6; ++j)
                #pragma unroll
                for (int r = 0; r < 4; ++r)
                    rm[r] = fmaxf(rm[r], acc[i][j][r]);
            #pragma unroll
            for (int msk = 1; msk <= 8; msk <<= 1)
                #pragma unroll
                for (int r = 0; r < 4; ++r)
                    rm[r] = fmaxf(rm[r], __shfl_xor(rm[r], msk));
            if (l15 == 0) {
                #pragma unroll
                for (int r = 0; r < 4; ++r)
                    rowbuf[wc * HW + wr * 96 + i * 16 + lq * 4 + r] = rm[r];
            }
        }
        __syncthreads();
        if (tid < HW) {
            float cmax = fmaxf(colbuf[tid], colbuf[HW + tid]);
            out[((size_t)g * B_ + p) * HW + tid] = cmax;
            float rmax = fmaxf(rowbuf[tid], rowbuf[HW + tid]);
            out[((size_t)p * B_ + g) * HW + tid] = rmax;
        }
    } else {
        // ================= PAM =================
        int b = bid - NTRI;
        unsigned short* qs = (unsigned short*)smem;            // [192][64] swz
        unsigned short* ks = qs + HW * C8_;
        float* red = (float*)(smem + 49152);                   // [4][48]
        const unsigned short* xb = xt + (size_t)b * HW * CC;
        int qc = w * 16 + l15;
        const float* wqp = Wq + (size_t)qc * CC;
        const float* wkp = Wk + (size_t)qc * CC;
        float bqv = bq[qc], bkv = bk[qc];

        // phase 1: q/k = xt[b] * W^T + bias -> LDS (chunk-swizzled rows)
        for (int mgrp = 0; mgrp < 4; ++mgrp) {
            int m0 = mgrp * 48;
            f32x4 accq[3], acck[3];
            #pragma unroll
            for (int i = 0; i < 3; ++i) {
                accq[i] = (f32x4){0.f, 0.f, 0.f, 0.f};
                acck[i] = (f32x4){0.f, 0.f, 0.f, 0.f};
            }
            for (int kt = 0; kt < 16; ++kt) {
                int ko8 = kt * 32 + lq * 8;
                bf16x8 af[3];
                #pragma unroll
                for (int i = 0; i < 3; ++i)
                    af[i] = *(const bf16x8*)(xb + (m0 + i * 16 + l15) * CC + ko8);
                u16x8 tq, tk;
                #pragma unroll
                for (int e = 0; e < 8; ++e) {
                    tq[e] = f2bf(wqp[ko8 + e]);
                    tk[e] = f2bf(wkp[ko8 + e]);
                }
                bf16x8 wqf = *(bf16x8*)&tq, wkf = *(bf16x8*)&tk;
                #pragma unroll
                for (int i = 0; i < 3; ++i) {
                    accq[i] = __builtin_amdgcn_mfma_f32_16x16x32_bf16(af[i], wqf, accq[i], 0, 0, 0);
                    acck[i] = __builtin_amdgcn_mfma_f32_16x16x32_bf16(af[i], wkf, acck[i], 0, 0, 0);
                }
            }
            #pragma unroll
            for (int i = 0; i < 3; ++i) {
                #pragma unroll
                for (int r = 0; r < 4; ++r) {
                    int m = m0 + i * 16 + lq * 4 + r;
                    int pos = m * 64 + ((((qc >> 3) ^ (m & 7)) << 3) | (qc & 7));
                    qs[pos] = f2bf(accq[i][r] + bqv);
                    ks[pos] = f2bf(acck[i][r] + bkv);
                }
            }
        }
        __syncthreads();

        // phase 2: energy = q k^T, fused row-max over n
        for (int mgrp = 0; mgrp < 4; ++mgrp) {
            int m0 = mgrp * 48;
            f32x4 acc[3][3];
            #pragma unroll
            for (int i = 0; i < 3; ++i)
                #pragma unroll
                for (int j = 0; j < 3; ++j)
                    acc[i][j] = (f32x4){0.f, 0.f, 0.f, 0.f};
            #pragma unroll
            for (int kt = 0; kt < 2; ++kt) {
                int lc = (kt << 2) | lq;              // logical k-chunk
                bf16x8 af[3], bfr[3];
                #pragma unroll
                for (int i = 0; i < 3; ++i) {
                    int m = m0 + i * 16 + l15;
                    af[i] = *(const bf16x8*)&qs[m * 64 + ((lc ^ (m & 7)) << 3)];
                }
                #pragma unroll
                for (int j = 0; j < 3; ++j) {
                    int n = w * 48 + j * 16 + l15;
                    bfr[j] = *(const bf16x8*)&ks[n * 64 + ((lc ^ (n & 7)) << 3)];
                }
                #pragma unroll
                for (int i = 0; i < 3; ++i)
                    #pragma unroll
                    for (int j = 0; j < 3; ++j)
                        acc[i][j] = __builtin_amdgcn_mfma_f32_16x16x32_bf16(
                            af[i], bfr[j], acc[i][j], 0, 0, 0);
            }
            #pragma unroll
            for (int i = 0; i < 3; ++i) {
                float rm[4];
                #pragma unroll
                for (int r = 0; r < 4; ++r) rm[r] = -1e30f;
                #pragma unroll
                for (int j = 0; j < 3; ++j)
                    #pragma unroll
                    for (int r = 0; r < 4; ++r)
                        rm[r] = fmaxf(rm[r], acc[i][j][r]);
                #pragma unroll
                for (int msk = 1; msk <= 8; msk <<= 1)
                    #pragma unroll
                    for (int r = 0; r < 4; ++r)
                        rm[r] = fmaxf(rm[r], __shfl_xor(rm[r], msk));
                if (l15 == 0) {
                    #pragma unroll
                    for (int r = 0; r < 4; ++r)
                        red[w * 48 + i * 16 + lq * 4 + r] = rm[r];
                }
            }
            __syncthreads();
            if (tid < 48) {
                float v = fmaxf(fmaxf(red[tid], red[48 + tid]),
                                fmaxf(red[96 + tid], red[144 + tid]));
                out[((size_t)B_ * B_ + b) * HW + m0 + tid] = v;
            }
            __syncthreads();
        }
    }
}

extern "C" void kernel_launch(void* const* d_in, const int* in_sizes, int n_in,
                              void* d_out, int out_size, void* d_ws, size_t ws_size,
                              hipStream_t stream) {
    (void)in_sizes; (void)n_in; (void)out_size; (void)ws_size;
    const float* x  = (const float*)d_in[0];
    const float* Wq = (const float*)d_in[1];
    const float* bq = (const float*)d_in[2];
    const float* Wk = (const float*)d_in[3];
    const float* bk = (const float*)d_in[4];
    float* out = (float*)d_out;

    unsigned short* xt = (unsigned short*)d_ws;   // 32*192*512*2 = 6291456 B

    k_transpose<<<dim3(96, 8), dim3(256), 0, stream>>>(x, xt);
    gram_pam<<<dim3(NBLK), dim3(256), 0, stream>>>(xt, Wq, bq, Wk, bk, out);
}